// Round 8
// baseline (32.045 us; speedup 1.0000x reference)
//
#include <hip/hip_runtime.h>

// Problem constants
//   N=16 samples, C=256 content channels, S=512 style channels, HW=64x64
//
// Algebraic reduction of the reference:
//   k[n][3][3]  = conv(style[n], dw_w) + dw_b               (9 scalars / sample)
//   s_d[n][c]   = mean over 4x4 of style[n][c]
//   pw1[n]      = s_d[n] . pw_kn_w + pw_kn_b                (1 scalar / sample)
//   bias[n][o]  = s_d[n] . pw_bias_w[o] + pw_bias_b[o]
//   Xs[n][h][w] = sum_c content[n][c][h][w]                 (channel sum)
//   D[n][h][w]  = 3x3 reflect-pad conv of Xs with k[n]
//   out[n][o][h][w] = 256*pw1[n]*D[n][h][w] + bias[n][o]
//
// K1: slim style stats (16 blocks) + channel-sum partials Xp (512 blocks).
// K2: 512 blocks x 8 planes (was 1024 x 4): halves the Xp-rebuild L2 traffic
//     and amortizes the rebuild/sync over 2x the stores. Bias dot first
//     (overlaps Xp loads), conv in registers, stores interleaved.

// workspace layout (floats)
#define OFF_SCALE 0                         // 16        : 256*pw1[n]
#define OFF_K     16                        // 16*9      : k[n][9]
#define OFF_SD    160                       // 16*512    : s_d[n][c]
#define OFF_XP    8352                      // 16*8*4096 : channel-sum partials

// ---------------------------------------------------------------- kernel 1
__global__ __launch_bounds__(256, 2) void ada_front(
    const float* __restrict__ style,      // (16,512,4,4)
    const float* __restrict__ content,    // (16,256,64,64)
    const float* __restrict__ dw_w,       // (1,512,2,2)
    const float* __restrict__ dw_b,       // (1,)
    const float* __restrict__ pw_kn_w,    // (1,512,1,1)
    const float* __restrict__ pw_kn_b,    // (1,)
    float* __restrict__ ws)
{
    const int t = threadIdx.x;
    __shared__ float red[4][10];

    if (blockIdx.x >= 16) {
        // ---- channel-sum partials (round-4/6/7 proven indexing)
        // Xp[n][g][p] = sum_{c in 32-ch group g} content[n][c][p]
        const int b  = blockIdx.x - 16;   // 512 blocks
        const int n  = b >> 5;            // 16 samples
        const int g  = (b >> 2) & 7;      // 8 groups of 32 channels
        const int pt = b & 3;             // 4 spatial quarters
        const int p4 = pt * 256 + t;      // float4 index in 64x64 plane [0,1024)

        const float4* src = (const float4*)content
                          + ((size_t)(n * 256 + g * 32)) * 1024 + p4;
        float4 a = make_float4(0.f, 0.f, 0.f, 0.f);
#pragma unroll 8
        for (int c = 0; c < 32; ++c) {
            float4 v = src[(size_t)c * 1024];
            a.x += v.x; a.y += v.y; a.z += v.z; a.w += v.w;
        }
        ((float4*)(ws + OFF_XP))[((size_t)(n * 8 + g)) * 1024 + p4] = a;
        return;
    }

    // ---- per-sample style stats (slim: k, scale, sd only)
    const int n = blockIdx.x;

    float acc[10];
#pragma unroll
    for (int j = 0; j < 10; ++j) acc[j] = 0.f;

#pragma unroll
    for (int cc = 0; cc < 2; ++cc) {
        const int c = t + cc * 256;
        const float4* sp = (const float4*)(style + ((size_t)n * 512 + c) * 16);
        float v[16];
#pragma unroll
        for (int q = 0; q < 4; ++q) {
            float4 f = sp[q];
            v[q*4+0] = f.x; v[q*4+1] = f.y; v[q*4+2] = f.z; v[q*4+3] = f.w;
        }
        float sum = 0.f;
#pragma unroll
        for (int q = 0; q < 16; ++q) sum += v[q];
        const float sdc = sum * 0.0625f;   // mean over 4x4
        ws[OFF_SD + n * 512 + c] = sdc;    // coalesced across t

        const float* w = dw_w + c * 4;     // [a*2+b]
        const float w00 = w[0], w01 = w[1], w10 = w[2], w11 = w[3];
#pragma unroll
        for (int ki = 0; ki < 3; ++ki)
#pragma unroll
            for (int kj = 0; kj < 3; ++kj)
                acc[ki*3+kj] += v[ki*4 + kj]       * w00
                              + v[ki*4 + kj + 1]   * w01
                              + v[(ki+1)*4 + kj]   * w10
                              + v[(ki+1)*4 + kj+1] * w11;
        acc[9] += sdc * pw_kn_w[c];
    }

    // wave(64)-level butterfly reduce of the 10 partials
#pragma unroll
    for (int off = 32; off >= 1; off >>= 1)
#pragma unroll
        for (int j = 0; j < 10; ++j)
            acc[j] += __shfl_down(acc[j], off, 64);

    if ((t & 63) == 0) {
#pragma unroll
        for (int j = 0; j < 10; ++j) red[t >> 6][j] = acc[j];
    }
    __syncthreads();

    if (t < 10) {
        const float s = red[0][t] + red[1][t] + red[2][t] + red[3][t];
        if (t < 9) ws[OFF_K + n * 9 + t] = s + dw_b[0];
        else       ws[OFF_SCALE + n]     = 256.f * (s + pw_kn_b[0]);
    }
}

// ---------------------------------------------------------------- kernel 2
// 512 blocks: block (n, s) -> planes s*8 .. s*8+7 of sample n.
//   1. bias dots (wave wv -> rows s*8+wv, s*8+wv+4), overlap Xp loads
//   2. Xs rebuild from 8 L2-resident partials into LDS
//   3. single sync; conv in registers per 4-point quad, 8 plane-stores each
__global__ __launch_bounds__(256, 2) void ada_back(
    const float* __restrict__ ws,
    const float* __restrict__ pw_bias_w,  // (256,512)
    const float* __restrict__ pw_bias_b,  // (256,)
    float4* __restrict__ out)
{
    const int bid = blockIdx.x;     // 512
    const int n   = bid >> 5;       // 16 samples
    const int s   = bid & 31;       // plane group: planes s*8 .. s*8+7
    const int t   = threadIdx.x;

    __shared__ float Xs[4096];      // channel-sum image, row-major 64x64
    __shared__ float bias_s[8];

    // ---- 1. per-block bias: wave wv computes rows s*8+wv and s*8+wv+4
    {
        const int wv = t >> 6, l = t & 63;
        const float4* sv = (const float4*)(ws + OFF_SD + (size_t)n * 512);
        const float4 s0 = sv[l * 2], s1 = sv[l * 2 + 1];
#pragma unroll
        for (int rr = 0; rr < 2; ++rr) {
            const int o = s * 8 + rr * 4 + wv;
            const float4* wr = (const float4*)(pw_bias_w + (size_t)o * 512);
            const float4 a0 = wr[l * 2], a1 = wr[l * 2 + 1];
            float d = a0.x*s0.x + a0.y*s0.y + a0.z*s0.z + a0.w*s0.w
                    + a1.x*s1.x + a1.y*s1.y + a1.z*s1.z + a1.w*s1.w;
#pragma unroll
            for (int off = 32; off >= 1; off >>= 1)
                d += __shfl_down(d, off, 64);
            if (l == 0) bias_s[rr * 4 + wv] = d + pw_bias_b[o];
        }
    }

    // ---- 2. Xs = sum of the 8 group partials (L2-resident)
    const float4* Xp = (const float4*)(ws + OFF_XP) + (size_t)n * 8 * 1024;
#pragma unroll
    for (int i = 0; i < 4; ++i) {
        const int p4 = i * 256 + t;
        float4 a = Xp[p4];
#pragma unroll
        for (int g = 1; g < 8; ++g) {
            float4 v = Xp[g * 1024 + p4];
            a.x += v.x; a.y += v.y; a.z += v.z; a.w += v.w;
        }
        ((float4*)Xs)[p4] = a;
    }

    float k[9];
#pragma unroll
    for (int j = 0; j < 9; ++j) k[j] = ws[OFF_K + n * 9 + j];
    const float scale = ws[OFF_SCALE + n];
    __syncthreads();                // Xs + bias_s ready

    float bl[8];
#pragma unroll
    for (int j = 0; j < 8; ++j) bl[j] = bias_s[j];
    float4* obase = out + ((size_t)(n * 256 + s * 8)) * 1024;

    // ---- 3. conv in registers + interleaved stores (8 planes per quad).
    // thread t, quad q -> points (h, w0..w0+3), h = q*16 + t/16, w0 = (t%16)*4
#pragma unroll
    for (int q = 0; q < 4; ++q) {
        const int h  = q * 16 + (t >> 4);
        const int w0 = (t & 15) * 4;
        const int hm = (h == 0)  ? 1  : h - 1;   // reflect (no edge repeat)
        const int hp = (h == 63) ? 62 : h + 1;
        float e0 = 0.f, e1 = 0.f, e2 = 0.f, e3 = 0.f;
        const int rows[3] = { hm, h, hp };
#pragma unroll
        for (int i = 0; i < 3; ++i) {
            const float* R = &Xs[rows[i] * 64];
            const float4 m    = *(const float4*)&R[w0];        // cols w0..w0+3
            const float  left  = (w0 == 0)  ? R[1]  : R[w0 - 1];
            const float  right = (w0 == 60) ? R[62] : R[w0 + 4];
            const float k0 = k[i*3], k1 = k[i*3+1], k2 = k[i*3+2];
            e0 += k0*left + k1*m.x + k2*m.y;
            e1 += k0*m.x  + k1*m.y + k2*m.z;
            e2 += k0*m.y  + k1*m.z + k2*m.w;
            e3 += k0*m.z  + k1*m.w + k2*right;
        }
        e0 *= scale; e1 *= scale; e2 *= scale; e3 *= scale;

        float4* o = obase + q * 256 + t;
#pragma unroll
        for (int pl = 0; pl < 8; ++pl) {
            const float b = bl[pl];
            o[pl * 1024] = make_float4(e0 + b, e1 + b, e2 + b, e3 + b);
        }
    }
}

// ---------------------------------------------------------------- launch
extern "C" void kernel_launch(void* const* d_in, const int* in_sizes, int n_in,
                              void* d_out, int out_size, void* d_ws, size_t ws_size,
                              hipStream_t stream)
{
    const float* style     = (const float*)d_in[0];
    const float* content   = (const float*)d_in[1];
    const float* dw_w      = (const float*)d_in[2];
    const float* dw_b      = (const float*)d_in[3];
    const float* pw_kn_w   = (const float*)d_in[4];
    const float* pw_kn_b   = (const float*)d_in[5];
    const float* pw_bias_w = (const float*)d_in[6];
    const float* pw_bias_b = (const float*)d_in[7];
    float*  ws  = (float*)d_ws;
    float4* out = (float4*)d_out;

    ada_front<<<16 + 512, 256, 0, stream>>>(style, content, dw_w, dw_b,
                                            pw_kn_w, pw_kn_b, ws);
    ada_back <<<512,      256, 0, stream>>>(ws, pw_bias_w, pw_bias_b, out);
}

// Round 9
// 29.985 us; speedup vs baseline: 1.0687x; 1.0687x over previous
//
#include <hip/hip_runtime.h>

// Problem constants
//   N=16 samples, C=256 content channels, S=512 style channels, HW=64x64
//
// Algebraic reduction of the reference:
//   k[n][3][3]  = conv(style[n], dw_w) + dw_b               (9 scalars / sample)
//   s_d[n][c]   = mean over 4x4 of style[n][c]
//   pw1[n]      = s_d[n] . pw_kn_w + pw_kn_b                (1 scalar / sample)
//   bias[n][o]  = s_d[n] . pw_bias_w[o] + pw_bias_b[o]
//   Xs[n][h][w] = sum_c content[n][c][h][w]                 (channel sum)
//   D[n][h][w]  = 3x3 reflect-pad conv of Xs with k[n]
//   out[n][o][h][w] = 256*pw1[n]*D[n][h][w] + bias[n][o]
//
// Round-8 lesson: K2's Xp-rebuild BYTE count isn't the limiter (halving it
// lost 1us); the lockstep pre-store serial section is. So K1 now reduces all
// 256 channels in-block (3-step LDS tree) and writes FINAL Xs (256 KB); K2's
// pre-store phase becomes one 16 KB coalesced L2 read.
//
// K1: style stats (blocks 0-15) + full channel-sum (blocks 16-527: 16 samples
//     x 32 plane-slices; 8 ch-groups/thread-col reduced via LDS tree).
// K2: 1024 blocks x 4 planes (round-7 proven shape): bias dot -> Xs 16 KB
//     load -> sync -> conv in registers + interleaved stores.

// workspace layout (floats)
#define OFF_SCALE 0                         // 16        : 256*pw1[n]
#define OFF_K     16                        // 16*9      : k[n][9]
#define OFF_SD    160                       // 16*512    : s_d[n][c]
#define OFF_XS    8352                      // 16*4096   : final channel-sum Xs

// ---------------------------------------------------------------- kernel 1
__global__ __launch_bounds__(256, 2) void ada_front(
    const float* __restrict__ style,      // (16,512,4,4)
    const float* __restrict__ content,    // (16,256,64,64)
    const float* __restrict__ dw_w,       // (1,512,2,2)
    const float* __restrict__ dw_b,       // (1,)
    const float* __restrict__ pw_kn_w,    // (1,512,1,1)
    const float* __restrict__ pw_kn_b,    // (1,)
    float* __restrict__ ws)
{
    const int t = threadIdx.x;
    __shared__ float red[4][10];
    __shared__ float4 part[8][32];

    if (blockIdx.x >= 16) {
        // ---- full channel-sum: block (n, slice) sums all 256 channels of a
        // 32-float4 slice. thread t: col = t&31, ch-group g = t>>5 (32 ch).
        const int b   = blockIdx.x - 16;  // 512 blocks
        const int n   = b >> 5;           // 16 samples
        const int sl  = b & 31;           // 32 slices of 32 float4
        const int col = t & 31;
        const int g   = t >> 5;

        const float4* src = (const float4*)content
                          + ((size_t)(n * 256 + g * 32)) * 1024 + sl * 32 + col;
        float4 a = make_float4(0.f, 0.f, 0.f, 0.f);
#pragma unroll 8
        for (int c = 0; c < 32; ++c) {
            float4 v = src[(size_t)c * 1024];
            a.x += v.x; a.y += v.y; a.z += v.z; a.w += v.w;
        }
        part[g][col] = a;
        __syncthreads();
        if (g < 4) {
            float4 v = part[g + 4][col], u = part[g][col];
            part[g][col] = make_float4(u.x + v.x, u.y + v.y, u.z + v.z, u.w + v.w);
        }
        __syncthreads();
        if (g < 2) {
            float4 v = part[g + 2][col], u = part[g][col];
            part[g][col] = make_float4(u.x + v.x, u.y + v.y, u.z + v.z, u.w + v.w);
        }
        __syncthreads();
        if (g == 0) {
            float4 v = part[1][col], u = part[0][col];
            ((float4*)(ws + OFF_XS))[(size_t)n * 1024 + sl * 32 + col] =
                make_float4(u.x + v.x, u.y + v.y, u.z + v.z, u.w + v.w);
        }
        return;
    }

    // ---- per-sample style stats (slim: k, scale, sd only)
    const int n = blockIdx.x;

    float acc[10];
#pragma unroll
    for (int j = 0; j < 10; ++j) acc[j] = 0.f;

#pragma unroll
    for (int cc = 0; cc < 2; ++cc) {
        const int c = t + cc * 256;
        const float4* sp = (const float4*)(style + ((size_t)n * 512 + c) * 16);
        float v[16];
#pragma unroll
        for (int q = 0; q < 4; ++q) {
            float4 f = sp[q];
            v[q*4+0] = f.x; v[q*4+1] = f.y; v[q*4+2] = f.z; v[q*4+3] = f.w;
        }
        float sum = 0.f;
#pragma unroll
        for (int q = 0; q < 16; ++q) sum += v[q];
        const float sdc = sum * 0.0625f;   // mean over 4x4
        ws[OFF_SD + n * 512 + c] = sdc;    // coalesced across t

        const float* w = dw_w + c * 4;     // [a*2+b]
        const float w00 = w[0], w01 = w[1], w10 = w[2], w11 = w[3];
#pragma unroll
        for (int ki = 0; ki < 3; ++ki)
#pragma unroll
            for (int kj = 0; kj < 3; ++kj)
                acc[ki*3+kj] += v[ki*4 + kj]       * w00
                              + v[ki*4 + kj + 1]   * w01
                              + v[(ki+1)*4 + kj]   * w10
                              + v[(ki+1)*4 + kj+1] * w11;
        acc[9] += sdc * pw_kn_w[c];
    }

    // wave(64)-level butterfly reduce of the 10 partials
#pragma unroll
    for (int off = 32; off >= 1; off >>= 1)
#pragma unroll
        for (int j = 0; j < 10; ++j)
            acc[j] += __shfl_down(acc[j], off, 64);

    if ((t & 63) == 0) {
#pragma unroll
        for (int j = 0; j < 10; ++j) red[t >> 6][j] = acc[j];
    }
    __syncthreads();

    if (t < 10) {
        const float s = red[0][t] + red[1][t] + red[2][t] + red[3][t];
        if (t < 9) ws[OFF_K + n * 9 + t] = s + dw_b[0];
        else       ws[OFF_SCALE + n]     = 256.f * (s + pw_kn_b[0]);
    }
}

// ---------------------------------------------------------------- kernel 2
// 1024 blocks: block (n, s) -> planes s*4 .. s*4+3 of sample n.
//   1. bias dot (wave wv -> row s*4+wv)
//   2. Xs load: one 16 KB coalesced L2 read into LDS
//   3. single sync; conv in registers per 4-point quad, stores interleaved
__global__ __launch_bounds__(256, 2) void ada_back(
    const float* __restrict__ ws,
    const float* __restrict__ pw_bias_w,  // (256,512)
    const float* __restrict__ pw_bias_b,  // (256,)
    float4* __restrict__ out)
{
    const int bid = blockIdx.x;     // 1024
    const int n   = bid >> 6;       // 16 samples
    const int s   = bid & 63;       // plane group
    const int t   = threadIdx.x;

    __shared__ float Xs[4096];      // channel-sum image, row-major 64x64
    __shared__ float bias_s[4];

    // ---- 1. per-block bias: wave wv computes row o = s*4 + wv
    {
        const int wv = t >> 6, l = t & 63;
        const int o  = s * 4 + wv;
        const float4* wr = (const float4*)(pw_bias_w + (size_t)o * 512);
        const float4* sv = (const float4*)(ws + OFF_SD + (size_t)n * 512);
        const float4 a0 = wr[l * 2],     a1 = wr[l * 2 + 1];
        const float4 s0 = sv[l * 2],     s1 = sv[l * 2 + 1];
        float d = a0.x*s0.x + a0.y*s0.y + a0.z*s0.z + a0.w*s0.w
                + a1.x*s1.x + a1.y*s1.y + a1.z*s1.z + a1.w*s1.w;
#pragma unroll
        for (int off = 32; off >= 1; off >>= 1)
            d += __shfl_down(d, off, 64);
        if (l == 0) bias_s[wv] = d + pw_bias_b[o];
    }

    // ---- 2. Xs: final channel-sum, one coalesced 16 KB read
    const float4* xg = (const float4*)(ws + OFF_XS) + (size_t)n * 1024;
#pragma unroll
    for (int i = 0; i < 4; ++i)
        ((float4*)Xs)[i * 256 + t] = xg[i * 256 + t];

    float k[9];
#pragma unroll
    for (int j = 0; j < 9; ++j) k[j] = ws[OFF_K + n * 9 + j];
    const float scale = ws[OFF_SCALE + n];
    __syncthreads();                // Xs + bias_s ready

    const float b0 = bias_s[0], b1 = bias_s[1], b2 = bias_s[2], b3 = bias_s[3];
    float4* obase = out + ((size_t)(n * 256 + s * 4)) * 1024;

    // ---- 3. conv in registers + interleaved stores.
    // thread t, quad q -> points (h, w0..w0+3), h = q*16 + t/16, w0 = (t%16)*4
#pragma unroll
    for (int q = 0; q < 4; ++q) {
        const int h  = q * 16 + (t >> 4);
        const int w0 = (t & 15) * 4;
        const int hm = (h == 0)  ? 1  : h - 1;   // reflect (no edge repeat)
        const int hp = (h == 63) ? 62 : h + 1;
        float e0 = 0.f, e1 = 0.f, e2 = 0.f, e3 = 0.f;
        const int rows[3] = { hm, h, hp };
#pragma unroll
        for (int i = 0; i < 3; ++i) {
            const float* R = &Xs[rows[i] * 64];
            const float4 m    = *(const float4*)&R[w0];        // cols w0..w0+3
            const float  left  = (w0 == 0)  ? R[1]  : R[w0 - 1];
            const float  right = (w0 == 60) ? R[62] : R[w0 + 4];
            const float k0 = k[i*3], k1 = k[i*3+1], k2 = k[i*3+2];
            e0 += k0*left + k1*m.x + k2*m.y;
            e1 += k0*m.x  + k1*m.y + k2*m.z;
            e2 += k0*m.y  + k1*m.z + k2*m.w;
            e3 += k0*m.z  + k1*m.w + k2*right;
        }
        e0 *= scale; e1 *= scale; e2 *= scale; e3 *= scale;

        float4* o = obase + q * 256 + t;
        o[0]    = make_float4(e0 + b0, e1 + b0, e2 + b0, e3 + b0);
        o[1024] = make_float4(e0 + b1, e1 + b1, e2 + b1, e3 + b1);
        o[2048] = make_float4(e0 + b2, e1 + b2, e2 + b2, e3 + b2);
        o[3072] = make_float4(e0 + b3, e1 + b3, e2 + b3, e3 + b3);
    }
}

// ---------------------------------------------------------------- launch
extern "C" void kernel_launch(void* const* d_in, const int* in_sizes, int n_in,
                              void* d_out, int out_size, void* d_ws, size_t ws_size,
                              hipStream_t stream)
{
    const float* style     = (const float*)d_in[0];
    const float* content   = (const float*)d_in[1];
    const float* dw_w      = (const float*)d_in[2];
    const float* dw_b      = (const float*)d_in[3];
    const float* pw_kn_w   = (const float*)d_in[4];
    const float* pw_kn_b   = (const float*)d_in[5];
    const float* pw_bias_w = (const float*)d_in[6];
    const float* pw_bias_b = (const float*)d_in[7];
    float*  ws  = (float*)d_ws;
    float4* out = (float4*)d_out;

    ada_front<<<16 + 512, 256, 0, stream>>>(style, content, dw_w, dw_b,
                                            pw_kn_w, pw_kn_b, ws);
    ada_back <<<1024,     256, 0, stream>>>(ws, pw_bias_w, pw_bias_b, out);
}